// Round 3
// baseline (8636.318 us; speedup 1.0000x reference)
//
#include <hip/hip_runtime.h>
#include <hip/hip_bf16.h>
#include <math.h>

#define S_LEN 1024
#define BATCH 4
#define M_ROWS 4096   // BATCH * S_LEN
#define DMODEL 1024
#define DFF 4096
#define NHEAD 8
#define DHEAD 128
#define WIN 100
#define LFWD 20

// ---------------- GEMM: C = act(A @ W + bias) (+resid), all fp32 ----------------
// A: M x K (row-major, stride K), W: K x Ncols slice of row-major matrix with
// row stride ldW, bias: Ncols (nullable), C: M x Ncols, resid: M x Ncols (nullable)
__global__ void gemm_kernel(const float* __restrict__ A, const float* __restrict__ W,
                            const float* __restrict__ bias, float* __restrict__ C,
                            const float* __restrict__ resid,
                            int M, int Ncols, int ldW, int K, int act)
{
    __shared__ float As[16][64];
    __shared__ float Bs[16][64];
    const int bm = blockIdx.y * 64;
    const int bn = blockIdx.x * 64;
    const int tid = threadIdx.x;
    const int tx = tid & 15, ty = tid >> 4;
    float acc[4][4] = {};
    for (int k0 = 0; k0 < K; k0 += 16) {
#pragma unroll
        for (int t = 0; t < 4; ++t) {
            int idx = tid + t * 256;
            int r = idx >> 4, c = idx & 15;
            As[c][r] = A[(size_t)(bm + r) * K + (k0 + c)];
        }
#pragma unroll
        for (int t = 0; t < 4; ++t) {
            int idx = tid + t * 256;
            int r = idx >> 6, c = idx & 63;
            Bs[r][c] = W[(size_t)(k0 + r) * ldW + (bn + c)];
        }
        __syncthreads();
#pragma unroll
        for (int kk = 0; kk < 16; ++kk) {
            float a[4], b[4];
#pragma unroll
            for (int i = 0; i < 4; ++i) a[i] = As[kk][ty * 4 + i];
#pragma unroll
            for (int j = 0; j < 4; ++j) b[j] = Bs[kk][tx * 4 + j];
#pragma unroll
            for (int i = 0; i < 4; ++i)
#pragma unroll
                for (int j = 0; j < 4; ++j)
                    acc[i][j] += a[i] * b[j];
        }
        __syncthreads();
    }
#pragma unroll
    for (int i = 0; i < 4; ++i) {
        int row = bm + ty * 4 + i;
#pragma unroll
        for (int j = 0; j < 4; ++j) {
            int col = bn + tx * 4 + j;
            float v = acc[i][j] + (bias ? bias[col] : 0.0f);
            if (act == 1) v = v / (1.0f + expf(-v));   // silu
            if (resid) v += resid[(size_t)row * Ncols + col];
            C[(size_t)row * Ncols + col] = v;
        }
    }
}

// ---------------- zero padded rows of h ----------------
__global__ void pad_kernel(float* __restrict__ h, const int* __restrict__ xlen)
{
    int row = blockIdx.x;            // b*1024 + s
    int b = row >> 10, s = row & 1023;
    int len = xlen[b] >> 2;          // // STRIDE
    if (s < len) return;
    for (int d = threadIdx.x; d < DMODEL; d += 256)
        h[(size_t)row * DMODEL + d] = 0.0f;
}

// ---------------- LayerNorm (row of 1024), fp32 ----------------
__global__ void ln_kernel(const float* __restrict__ x, const float* __restrict__ sc,
                          const float* __restrict__ bi, float* __restrict__ y)
{
    int row = blockIdx.x;
    const float* xr = x + (size_t)row * DMODEL;
    float vals[4];
    float lsum = 0.0f, lsq = 0.0f;
#pragma unroll
    for (int t = 0; t < 4; ++t) {
        float v = xr[threadIdx.x + 256 * t];
        vals[t] = v; lsum += v; lsq += v * v;
    }
    for (int o = 32; o > 0; o >>= 1) {
        lsum += __shfl_down(lsum, o, 64);
        lsq  += __shfl_down(lsq,  o, 64);
    }
    __shared__ float s1[4], s2[4];
    int wv = threadIdx.x >> 6, ln = threadIdx.x & 63;
    if (ln == 0) { s1[wv] = lsum; s2[wv] = lsq; }
    __syncthreads();
    if (threadIdx.x == 0) {
        float a = s1[0] + s1[1] + s1[2] + s1[3];
        float b = s2[0] + s2[1] + s2[2] + s2[3];
        float mu = a * (1.0f / DMODEL);
        float var = b * (1.0f / DMODEL) - mu * mu;
        s1[0] = mu;
        s2[0] = rsqrtf(fmaxf(var, 0.0f) + 1e-5f);
    }
    __syncthreads();
    float mu = s1[0], inv = s2[0];
#pragma unroll
    for (int t = 0; t < 4; ++t) {
        int d = threadIdx.x + 256 * t;
        y[(size_t)row * DMODEL + d] = (vals[t] - mu) * inv * sc[d] + bi[d];
    }
}

// ---------------- RoPE (in-place on q and k), fp32 ----------------
__global__ void rope_kernel(float* __restrict__ q, float* __restrict__ k)
{
    size_t idx = (size_t)blockIdx.x * 256 + threadIdx.x;  // over B*S*H*64
    int d = idx & 63;
    size_t rest = idx >> 6;          // (b*1024+s)*8 + h
    int hh = rest & 7;
    int s = (rest >> 3) & 1023;
    size_t base = (rest >> 3) * DMODEL + (size_t)hh * DHEAD;
    float inv = powf(10000.0f, -(float)d / 64.0f);
    float ang = (float)s * inv;
    float c = cosf(ang);
    float si = sinf(ang);
    {
        float x1 = q[base + d], x2 = q[base + 64 + d];
        q[base + d]      = x1 * c - x2 * si;
        q[base + 64 + d] = x1 * si + x2 * c;
    }
    {
        float x1 = k[base + d], x2 = k[base + 64 + d];
        k[base + d]      = x1 * c - x2 * si;
        k[base + 64 + d] = x1 * si + x2 * c;
    }
}

// ---------------- mean of v over all s, per (b,h) ----------------
__global__ void vmean_kernel(const float* __restrict__ v, float* __restrict__ vmean)
{
    int bh = blockIdx.x;             // b*8 + h
    int b = bh >> 3, hh = bh & 7;
    int d = threadIdx.x;             // 128 threads
    float acc = 0.0f;
    for (int s = 0; s < S_LEN; ++s)
        acc += v[((size_t)(b * S_LEN + s)) * DMODEL + hh * DHEAD + d];
    vmean[(size_t)bh * DHEAD + d] = acc * (1.0f / S_LEN);
}

// ---------------- windowed attention, one wave per (b,h,i) ----------------
__global__ void attn_kernel(const float* __restrict__ q, const float* __restrict__ k,
                            const float* __restrict__ v, const float* __restrict__ vmean,
                            const int* __restrict__ xlen, float* __restrict__ ctx)
{
    const int lane = threadIdx.x;    // 64
    int bhi = blockIdx.x;
    int i = bhi & 1023;
    int hh = (bhi >> 10) & 7;
    int b = bhi >> 13;
    int len = xlen[b] >> 2;
    size_t rowoff = ((size_t)(b * S_LEN + i)) * DMODEL + hh * DHEAD;
    int j0 = i - (WIN - 1); if (j0 < 0) j0 = 0;
    if (j0 >= len) {
        // fully-masked row: softmax uniform over ALL keys -> ctx = mean(v)
        const float* vm = vmean + (size_t)(b * NHEAD + hh) * DHEAD;
        ctx[rowoff + lane]      = vm[lane];
        ctx[rowoff + 64 + lane] = vm[64 + lane];
        return;
    }
    int j1 = i + LFWD; if (j1 > S_LEN - 1) j1 = S_LEN - 1;
    if (j1 > len - 1) j1 = len - 1;     // keys >= len masked (exp underflows to 0)

    __shared__ float qs[DHEAD];
    __shared__ float p[128];
    qs[lane]      = q[rowoff + lane];
    qs[lane + 64] = q[rowoff + 64 + lane];
    __syncthreads();

    const float scale = 0.088388347648318447f;  // 1/sqrt(128)
    int jA = j0 + lane, jB = j0 + 64 + lane;
    float s0 = -1e30f, s1 = -1e30f;
    if (jA <= j1) {
        const float* kr = k + ((size_t)(b * S_LEN + jA)) * DMODEL + hh * DHEAD;
        float acc = 0.0f;
#pragma unroll 8
        for (int d = 0; d < DHEAD; ++d) acc += qs[d] * kr[d];
        s0 = acc * scale;
    }
    if (jB <= j1) {
        const float* kr = k + ((size_t)(b * S_LEN + jB)) * DMODEL + hh * DHEAD;
        float acc = 0.0f;
#pragma unroll 8
        for (int d = 0; d < DHEAD; ++d) acc += qs[d] * kr[d];
        s1 = acc * scale;
    }
    float m = fmaxf(s0, s1);
    for (int o = 32; o > 0; o >>= 1) m = fmaxf(m, __shfl_down(m, o, 64));
    m = __shfl(m, 0, 64);
    float e0 = (jA <= j1) ? __expf(s0 - m) : 0.0f;
    float e1 = (jB <= j1) ? __expf(s1 - m) : 0.0f;
    float ssum = e0 + e1;
    for (int o = 32; o > 0; o >>= 1) ssum += __shfl_down(ssum, o, 64);
    ssum = __shfl(ssum, 0, 64);
    float inv = 1.0f / fmaxf(ssum, 1e-30f);
    p[lane] = e0 * inv;
    p[lane + 64] = e1 * inv;
    __syncthreads();

    float a0 = 0.0f, a1 = 0.0f;
    for (int j = j0; j <= j1; ++j) {
        float pj = p[j - j0];
        const float* vr = v + ((size_t)(b * S_LEN + j)) * DMODEL + hh * DHEAD;
        a0 += pj * vr[lane];
        a1 += pj * vr[64 + lane];
    }
    ctx[rowoff + lane]      = a0;
    ctx[rowoff + 64 + lane] = a1;
}

extern "C" void kernel_launch(void* const* d_in, const int* in_sizes, int n_in,
                              void* d_out, int out_size, void* d_ws, size_t ws_size,
                              hipStream_t stream)
{
    const float* x      = (const float*)d_in[0];   // (4,4096,512) == (4096,2048)
    const int*   xlen   = (const int*)d_in[1];
    const float* Wp     = (const float*)d_in[2];
    const float* bp     = (const float*)d_in[3];
    const float* ln1_s  = (const float*)d_in[4];
    const float* ln1_b  = (const float*)d_in[5];
    const float* Wq     = (const float*)d_in[6];
    const float* bq     = (const float*)d_in[7];
    const float* Wk     = (const float*)d_in[8];
    const float* bk     = (const float*)d_in[9];
    const float* Wv     = (const float*)d_in[10];
    const float* bv     = (const float*)d_in[11];
    const float* Wo     = (const float*)d_in[12];
    const float* bo     = (const float*)d_in[13];
    const float* ln2_s  = (const float*)d_in[14];
    const float* ln2_b  = (const float*)d_in[15];
    const float* W1     = (const float*)d_in[16];
    const float* b1     = (const float*)d_in[17];
    const float* W2     = (const float*)d_in[18];
    const float* b2     = (const float*)d_in[19];
    const float* lnf_s  = (const float*)d_in[20];
    const float* lnf_b  = (const float*)d_in[21];
    (void)in_sizes; (void)n_in; (void)out_size; (void)ws_size;

    // ---- workspace layout: 64 MB + 16 KB, all fp32 ----
    const size_t MD = (size_t)M_ROWS * DMODEL;       // 4M elems
    float* h     = (float*)d_ws;                     // 16 MB (residual stream)
    float* y     = h + MD;                           // 16 MB (LN out / ctx)
    float* qb    = y + MD;                           // 16 MB (q / ffn-mid chunk)
    float* kb    = qb + MD;                          // 16 MB
    float* vmean = kb + MD;                          // 16 KB
    float* vb    = (float*)d_out;                    // 16 MB scratch; final LN overwrites

    dim3 blk(256);
    dim3 g_n1(DMODEL / 64, M_ROWS / 64);   // Ncols=1024

    // projection: h = x @ Wp + bp
    gemm_kernel<<<g_n1, blk, 0, stream>>>(x, Wp, bp, h, nullptr,
                                          M_ROWS, DMODEL, DMODEL, 2048, 0);
    pad_kernel<<<M_ROWS, blk, 0, stream>>>(h, xlen);

    for (int l = 0; l < 4; ++l) {
        const size_t wD  = (size_t)l * DMODEL * DMODEL;
        const size_t wF  = (size_t)l * DMODEL * DFF;   // W1
        const size_t wF2 = (size_t)l * DFF * DMODEL;   // W2
        const size_t vD  = (size_t)l * DMODEL;
        const size_t vF  = (size_t)l * DFF;

        ln_kernel<<<M_ROWS, blk, 0, stream>>>(h, ln1_s + vD, ln1_b + vD, y);

        gemm_kernel<<<g_n1, blk, 0, stream>>>(y, Wq + wD, bq + vD, qb,
                                              nullptr, M_ROWS, DMODEL, DMODEL, DMODEL, 0);
        gemm_kernel<<<g_n1, blk, 0, stream>>>(y, Wk + wD, bk + vD, kb,
                                              nullptr, M_ROWS, DMODEL, DMODEL, DMODEL, 0);
        gemm_kernel<<<g_n1, blk, 0, stream>>>(y, Wv + wD, bv + vD, vb,
                                              nullptr, M_ROWS, DMODEL, DMODEL, DMODEL, 0);

        rope_kernel<<<(M_ROWS * NHEAD * 64) / 256, blk, 0, stream>>>(qb, kb);
        vmean_kernel<<<BATCH * NHEAD, dim3(DHEAD), 0, stream>>>(vb, vmean);
        attn_kernel<<<BATCH * NHEAD * S_LEN, dim3(64), 0, stream>>>(qb, kb, vb, vmean,
                                                                    xlen, y);

        // h = h + ctx @ Wo + bo   (ctx lives in y)
        gemm_kernel<<<g_n1, blk, 0, stream>>>(y, Wo + wD, bo + vD, h,
                                              h, M_ROWS, DMODEL, DMODEL, DMODEL, 0);

        ln_kernel<<<M_ROWS, blk, 0, stream>>>(h, ln2_s + vD, ln2_b + vD, y);

        // FFN in 4 column-chunks of 1024: mid_c = silu(y @ W1[:,c] + b1[c]);
        // h = h + mid_c @ W2[c*1024:(c+1)*1024, :] (+ b2 on first chunk)
        for (int c = 0; c < 4; ++c) {
            gemm_kernel<<<g_n1, blk, 0, stream>>>(
                y, W1 + wF + (size_t)c * 1024, b1 + vF + (size_t)c * 1024, qb,
                nullptr, M_ROWS, 1024, DFF, DMODEL, 1);
            gemm_kernel<<<g_n1, blk, 0, stream>>>(
                qb, W2 + wF2 + (size_t)c * 1024 * DMODEL, (c == 0) ? (b2 + vD) : nullptr, h,
                h, M_ROWS, DMODEL, DMODEL, 1024, 0);
        }
    }

    ln_kernel<<<M_ROWS, blk, 0, stream>>>(h, lnf_s, lnf_b, (float*)d_out);
}

// Round 4
// 2570.561 us; speedup vs baseline: 3.3597x; 3.3597x over previous
//
#include <hip/hip_runtime.h>
#include <hip/hip_bf16.h>
#include <math.h>

typedef __hip_bfloat16 bf16;
typedef __attribute__((ext_vector_type(8))) short short8;
typedef __attribute__((ext_vector_type(4))) float f32x4;

#define S_LEN 1024
#define BATCH 4
#define M_ROWS 4096
#define DMODEL 1024
#define DFF 4096
#define NHEAD 8
#define DHEAD 128
#define WIN 100
#define LFWD 20

__device__ __forceinline__ void gl_lds16(const void* g, void* l) {
    __builtin_amdgcn_global_load_lds(
        (const __attribute__((address_space(1))) void*)g,
        (__attribute__((address_space(3))) void*)l, 16, 0, 0);
}

// ---------------- MFMA GEMM: C = act(A @ Bt^T + bias) (+resid) ----------------
// A: M x K bf16 row-major (stride K). Bt: N x K bf16 row-major (W^T).
// bias fp32 (nullable), resid fp32 M x N (nullable), C: M x N (TC).
// Tile 128x128, BK=32, 4 waves each computing 64x64 (4x4 MFMA 16x16x32 frags).
template<typename TC>
__global__ __launch_bounds__(256)
void mfma_gemm(const bf16* __restrict__ A, const bf16* __restrict__ Bt,
               const float* __restrict__ bias, TC* __restrict__ C,
               const float* __restrict__ resid, int M, int N, int K, int act)
{
    __shared__ bf16 As[128 * 32];
    __shared__ bf16 Bs[128 * 32];
    const int bm = blockIdx.y * 128;
    const int bn = blockIdx.x * 128;
    const int tid = threadIdx.x;
    const int w = tid >> 6, lane = tid & 63;
    const int wm = (w & 1) * 64, wn = (w >> 1) * 64;

    // staging: wave w covers rows [w*32, w*32+32), 2 issues x 16 rows;
    // lane l -> row l>>2, 16-byte chunk (l&3) within the 64 B row.
    const int srow = w * 32 + (lane >> 2);
    const int selem = (lane & 3) * 8;  // bf16 elems
    const bf16* ga0 = A + (size_t)(bm + srow) * K + selem;
    const bf16* ga1 = ga0 + (size_t)16 * K;
    const bf16* gb0 = Bt + (size_t)(bn + srow) * K + selem;
    const bf16* gb1 = gb0 + (size_t)16 * K;
    bf16* la0 = As + (w * 32) * 32;
    bf16* la1 = As + (w * 32 + 16) * 32;
    bf16* lb0 = Bs + (w * 32) * 32;
    bf16* lb1 = Bs + (w * 32 + 16) * 32;

    f32x4 acc[4][4] = {};
    const int koff = (lane >> 4) * 8;
    const int fr = lane & 15;

    for (int k0 = 0; k0 < K; k0 += 32) {
        gl_lds16(ga0, la0); gl_lds16(ga1, la1);
        gl_lds16(gb0, lb0); gl_lds16(gb1, lb1);
        ga0 += 32; ga1 += 32; gb0 += 32; gb1 += 32;
        __syncthreads();            // drains vmcnt -> tiles visible
        short8 af[4], bfr[4];
#pragma unroll
        for (int i = 0; i < 4; ++i)
            af[i] = *(const short8*)(As + (wm + i * 16 + fr) * 32 + koff);
#pragma unroll
        for (int j = 0; j < 4; ++j)
            bfr[j] = *(const short8*)(Bs + (wn + j * 16 + fr) * 32 + koff);
#pragma unroll
        for (int i = 0; i < 4; ++i)
#pragma unroll
            for (int j = 0; j < 4; ++j)
                acc[i][j] = __builtin_amdgcn_mfma_f32_16x16x32_bf16(
                    af[i], bfr[j], acc[i][j], 0, 0, 0);
        __syncthreads();            // all reads done before next overwrite
    }

    const int cq = lane >> 4, cn = lane & 15;
#pragma unroll
    for (int i = 0; i < 4; ++i) {
#pragma unroll
        for (int r = 0; r < 4; ++r) {
            int row = bm + wm + i * 16 + cq * 4 + r;
#pragma unroll
            for (int j = 0; j < 4; ++j) {
                int col = bn + wn + j * 16 + cn;
                float v = acc[i][j][r];
                if (bias) v += bias[col];
                if (act)  v = v / (1.0f + __expf(-v));   // silu
                if (resid) v += resid[(size_t)row * N + col];
                C[(size_t)row * N + col] = (TC)v;
            }
        }
    }
}

// ---------------- transpose+cast: W (K x N fp32, row stride ld) -> Wt (N x K bf16) ----
__global__ void transpose_kernel(const float* __restrict__ W, bf16* __restrict__ Wt,
                                 int K, int N, int ld)
{
    __shared__ float t[32][33];
    const int n0 = blockIdx.x * 32, k0 = blockIdx.y * 32;
    const int tx = threadIdx.x & 31, ty = threadIdx.x >> 5;   // ty 0..7
#pragma unroll
    for (int i = 0; i < 32; i += 8)
        t[ty + i][tx] = W[(size_t)(k0 + ty + i) * ld + n0 + tx];
    __syncthreads();
#pragma unroll
    for (int i = 0; i < 32; i += 8)
        Wt[(size_t)(n0 + ty + i) * K + k0 + tx] = (bf16)t[tx][ty + i];
}

// ---------------- fp32 -> bf16 convert (x) ----------------
__global__ void cvt_kernel(const float* __restrict__ s, bf16* __restrict__ d)
{
    size_t i = ((size_t)blockIdx.x * 256 + threadIdx.x) * 4;
    float4 v = *(const float4*)(s + i);
    d[i] = (bf16)v.x; d[i + 1] = (bf16)v.y; d[i + 2] = (bf16)v.z; d[i + 3] = (bf16)v.w;
}

// ---------------- zero padded rows of h ----------------
__global__ void pad_kernel(float* __restrict__ h, const int* __restrict__ xlen)
{
    int row = blockIdx.x;
    int b = row >> 10, s = row & 1023;
    int len = xlen[b] >> 2;
    if (s < len) return;
    for (int d = threadIdx.x; d < DMODEL; d += 256)
        h[(size_t)row * DMODEL + d] = 0.0f;
}

// ---------------- LayerNorm (row of 1024), fp32 in, TO out ----------------
template<typename TO>
__global__ void ln_kernel(const float* __restrict__ x, const float* __restrict__ sc,
                          const float* __restrict__ bi, TO* __restrict__ y)
{
    int row = blockIdx.x;
    const float* xr = x + (size_t)row * DMODEL;
    float vals[4];
    float lsum = 0.0f, lsq = 0.0f;
#pragma unroll
    for (int t = 0; t < 4; ++t) {
        float v = xr[threadIdx.x + 256 * t];
        vals[t] = v; lsum += v; lsq += v * v;
    }
    for (int o = 32; o > 0; o >>= 1) {
        lsum += __shfl_down(lsum, o, 64);
        lsq  += __shfl_down(lsq,  o, 64);
    }
    __shared__ float s1[4], s2[4];
    int wv = threadIdx.x >> 6, ln = threadIdx.x & 63;
    if (ln == 0) { s1[wv] = lsum; s2[wv] = lsq; }
    __syncthreads();
    if (threadIdx.x == 0) {
        float a = s1[0] + s1[1] + s1[2] + s1[3];
        float b = s2[0] + s2[1] + s2[2] + s2[3];
        float mu = a * (1.0f / DMODEL);
        float var = b * (1.0f / DMODEL) - mu * mu;
        s1[0] = mu;
        s2[0] = rsqrtf(fmaxf(var, 0.0f) + 1e-5f);
    }
    __syncthreads();
    float mu = s1[0], inv = s2[0];
#pragma unroll
    for (int t = 0; t < 4; ++t) {
        int d = threadIdx.x + 256 * t;
        y[(size_t)row * DMODEL + d] = (TO)((vals[t] - mu) * inv * sc[d] + bi[d]);
    }
}

// ---------------- RoPE (in-place, bf16) ----------------
__global__ void rope_kernel(bf16* __restrict__ q, bf16* __restrict__ k)
{
    size_t idx = (size_t)blockIdx.x * 256 + threadIdx.x;  // over B*S*H*64
    int d = idx & 63;
    size_t rest = idx >> 6;
    int hh = rest & 7;
    int s = (rest >> 3) & 1023;
    size_t base = (rest >> 3) * DMODEL + (size_t)hh * DHEAD;
    float inv = powf(10000.0f, -(float)d / 64.0f);
    float ang = (float)s * inv;
    float c = cosf(ang), si = sinf(ang);
    {
        float x1 = (float)q[base + d], x2 = (float)q[base + 64 + d];
        q[base + d]      = (bf16)(x1 * c - x2 * si);
        q[base + 64 + d] = (bf16)(x1 * si + x2 * c);
    }
    {
        float x1 = (float)k[base + d], x2 = (float)k[base + 64 + d];
        k[base + d]      = (bf16)(x1 * c - x2 * si);
        k[base + 64 + d] = (bf16)(x1 * si + x2 * c);
    }
}

// ---------------- mean of v over all s, per (b,h) ----------------
__global__ void vmean_kernel(const bf16* __restrict__ v, float* __restrict__ vmean)
{
    int bh = blockIdx.x;
    int b = bh >> 3, hh = bh & 7;
    int d = threadIdx.x;  // 128
    float acc = 0.0f;
    for (int s = 0; s < S_LEN; ++s)
        acc += (float)v[((size_t)(b * S_LEN + s)) * DMODEL + hh * DHEAD + d];
    vmean[(size_t)bh * DHEAD + d] = acc * (1.0f / S_LEN);
}

// ---------------- windowed attention, one wave per (b,h,i) ----------------
__global__ void attn_kernel(const bf16* __restrict__ q, const bf16* __restrict__ k,
                            const bf16* __restrict__ v, const float* __restrict__ vmean,
                            const int* __restrict__ xlen, bf16* __restrict__ ctx)
{
    const int lane = threadIdx.x;  // 64
    int bhi = blockIdx.x;
    int i = bhi & 1023;
    int hh = (bhi >> 10) & 7;
    int b = bhi >> 13;
    int len = xlen[b] >> 2;
    size_t rowoff = ((size_t)(b * S_LEN + i)) * DMODEL + hh * DHEAD;
    int j0 = i - (WIN - 1); if (j0 < 0) j0 = 0;
    if (j0 >= len) {
        const float* vm = vmean + (size_t)(b * NHEAD + hh) * DHEAD;
        ctx[rowoff + lane]      = (bf16)vm[lane];
        ctx[rowoff + 64 + lane] = (bf16)vm[64 + lane];
        return;
    }
    int j1 = i + LFWD; if (j1 > S_LEN - 1) j1 = S_LEN - 1;
    if (j1 > len - 1) j1 = len - 1;

    __shared__ float qs[DHEAD];
    __shared__ float p[128];
    qs[lane]      = (float)q[rowoff + lane];
    qs[lane + 64] = (float)q[rowoff + 64 + lane];
    __syncthreads();

    const float scale = 0.088388347648318447f;  // 1/sqrt(128)
    int jA = j0 + lane, jB = j0 + 64 + lane;
    float s0 = -1e30f, s1 = -1e30f;
    if (jA <= j1) {
        const bf16* kr = k + ((size_t)(b * S_LEN + jA)) * DMODEL + hh * DHEAD;
        float acc = 0.0f;
#pragma unroll 8
        for (int d = 0; d < DHEAD; ++d) acc += qs[d] * (float)kr[d];
        s0 = acc * scale;
    }
    if (jB <= j1) {
        const bf16* kr = k + ((size_t)(b * S_LEN + jB)) * DMODEL + hh * DHEAD;
        float acc = 0.0f;
#pragma unroll 8
        for (int d = 0; d < DHEAD; ++d) acc += qs[d] * (float)kr[d];
        s1 = acc * scale;
    }
    float m = fmaxf(s0, s1);
    for (int o = 32; o > 0; o >>= 1) m = fmaxf(m, __shfl_down(m, o, 64));
    m = __shfl(m, 0, 64);
    float e0 = (jA <= j1) ? __expf(s0 - m) : 0.0f;
    float e1 = (jB <= j1) ? __expf(s1 - m) : 0.0f;
    float ssum = e0 + e1;
    for (int o = 32; o > 0; o >>= 1) ssum += __shfl_down(ssum, o, 64);
    ssum = __shfl(ssum, 0, 64);
    float inv = 1.0f / fmaxf(ssum, 1e-30f);
    p[lane] = e0 * inv;
    p[lane + 64] = e1 * inv;
    __syncthreads();

    float a0 = 0.0f, a1 = 0.0f;
    for (int j = j0; j <= j1; ++j) {
        float pj = p[j - j0];
        const bf16* vr = v + ((size_t)(b * S_LEN + j)) * DMODEL + hh * DHEAD;
        a0 += pj * (float)vr[lane];
        a1 += pj * (float)vr[64 + lane];
    }
    ctx[rowoff + lane]      = (bf16)a0;
    ctx[rowoff + 64 + lane] = (bf16)a1;
}

extern "C" void kernel_launch(void* const* d_in, const int* in_sizes, int n_in,
                              void* d_out, int out_size, void* d_ws, size_t ws_size,
                              hipStream_t stream)
{
    const float* x      = (const float*)d_in[0];
    const int*   xlen   = (const int*)d_in[1];
    const float* Wp     = (const float*)d_in[2];
    const float* bp     = (const float*)d_in[3];
    const float* ln1_s  = (const float*)d_in[4];
    const float* ln1_b  = (const float*)d_in[5];
    const float* Wq     = (const float*)d_in[6];
    const float* bq     = (const float*)d_in[7];
    const float* Wk     = (const float*)d_in[8];
    const float* bk     = (const float*)d_in[9];
    const float* Wv     = (const float*)d_in[10];
    const float* bv     = (const float*)d_in[11];
    const float* Wo     = (const float*)d_in[12];
    const float* bo     = (const float*)d_in[13];
    const float* W1     = (const float*)d_in[16];
    const float* b1     = (const float*)d_in[17];
    const float* W2     = (const float*)d_in[18];
    const float* b2     = (const float*)d_in[19];
    const float* ln2_s  = (const float*)d_in[14];
    const float* ln2_b  = (const float*)d_in[15];
    const float* lnf_s  = (const float*)d_in[20];
    const float* lnf_b  = (const float*)d_in[21];
    (void)in_sizes; (void)n_in; (void)out_size; (void)ws_size;

    // ---- workspace: 56 MB + 16 KB ----
    const size_t MD = (size_t)M_ROWS * DMODEL;          // 4M
    float* h     = (float*)d_ws;                        // 16 MB
    bf16*  y     = (bf16*)(h + MD);                     // 8 MB (LN out / ctx)
    bf16*  qb    = y + MD;                              // 8 MB
    bf16*  kb    = qb + MD;                             // 8 MB
    bf16*  big   = kb + MD;                             // 16 MB: xb (4096x2048) / mid chunk
    float* vmean = (float*)(big + 2 * MD);              // 16 KB
    // d_out (16 MB fp32) doubles as scratch until the final LN overwrites it:
    bf16*  vb    = (bf16*)d_out;                        // [0, 8 MB)
    bf16*  wt    = (bf16*)d_out + 4 * MD / 1;           // careful: elems
    wt = (bf16*)((char*)d_out + 8 * 1024 * 1024);       // [8 MB, 12 MB), max 4 MB

    dim3 blk(256);
    dim3 gT_1k(DMODEL / 32, DMODEL / 32);               // transpose 1024x1024
    dim3 gG_n1(DMODEL / 128, M_ROWS / 128);             // GEMM N=1024

    // xb = bf16(x); h = xb @ WpT^T + bp; pad
    cvt_kernel<<<(2 * MD) / (256 * 4), blk, 0, stream>>>(x, big);
    transpose_kernel<<<dim3(DMODEL / 32, 2048 / 32), blk, 0, stream>>>(Wp, wt, 2048, DMODEL, DMODEL);
    mfma_gemm<float><<<gG_n1, blk, 0, stream>>>(big, wt, bp, h, nullptr,
                                                M_ROWS, DMODEL, 2048, 0);
    pad_kernel<<<M_ROWS, blk, 0, stream>>>(h, xlen);

    for (int l = 0; l < 4; ++l) {
        const size_t wD  = (size_t)l * DMODEL * DMODEL;
        const size_t wF  = (size_t)l * DMODEL * DFF;   // W1 (1024 x 4096)
        const size_t wF2 = (size_t)l * DFF * DMODEL;   // W2 (4096 x 1024)
        const size_t vD  = (size_t)l * DMODEL;
        const size_t vF  = (size_t)l * DFF;

        ln_kernel<bf16><<<M_ROWS, blk, 0, stream>>>(h, ln1_s + vD, ln1_b + vD, y);

        transpose_kernel<<<gT_1k, blk, 0, stream>>>(Wq + wD, wt, DMODEL, DMODEL, DMODEL);
        mfma_gemm<bf16><<<gG_n1, blk, 0, stream>>>(y, wt, bq + vD, qb, nullptr,
                                                   M_ROWS, DMODEL, DMODEL, 0);
        transpose_kernel<<<gT_1k, blk, 0, stream>>>(Wk + wD, wt, DMODEL, DMODEL, DMODEL);
        mfma_gemm<bf16><<<gG_n1, blk, 0, stream>>>(y, wt, bk + vD, kb, nullptr,
                                                   M_ROWS, DMODEL, DMODEL, 0);
        transpose_kernel<<<gT_1k, blk, 0, stream>>>(Wv + wD, wt, DMODEL, DMODEL, DMODEL);
        mfma_gemm<bf16><<<gG_n1, blk, 0, stream>>>(y, wt, bv + vD, vb, nullptr,
                                                   M_ROWS, DMODEL, DMODEL, 0);

        rope_kernel<<<(M_ROWS * NHEAD * 64) / 256, blk, 0, stream>>>(qb, kb);
        vmean_kernel<<<BATCH * NHEAD, dim3(DHEAD), 0, stream>>>(vb, vmean);
        attn_kernel<<<BATCH * NHEAD * S_LEN, dim3(64), 0, stream>>>(qb, kb, vb, vmean,
                                                                    xlen, y);

        transpose_kernel<<<gT_1k, blk, 0, stream>>>(Wo + wD, wt, DMODEL, DMODEL, DMODEL);
        mfma_gemm<float><<<gG_n1, blk, 0, stream>>>(y, wt, bo + vD, h, h,
                                                    M_ROWS, DMODEL, DMODEL, 0);

        ln_kernel<bf16><<<M_ROWS, blk, 0, stream>>>(h, ln2_s + vD, ln2_b + vD, y);

        // FFN in 2 column-chunks of 2048
        for (int c = 0; c < 2; ++c) {
            // mid = silu(y @ W1[:, c*2048 : +2048] + b1[...])
            transpose_kernel<<<dim3(2048 / 32, DMODEL / 32), blk, 0, stream>>>(
                W1 + wF + (size_t)c * 2048, wt, DMODEL, 2048, DFF);
            mfma_gemm<bf16><<<dim3(2048 / 128, M_ROWS / 128), blk, 0, stream>>>(
                y, wt, b1 + vF + (size_t)c * 2048, big, nullptr,
                M_ROWS, 2048, DMODEL, 1);
            // h = h + mid @ W2[c*2048 : +2048, :] (+ b2 on first chunk)
            transpose_kernel<<<dim3(DMODEL / 32, 2048 / 32), blk, 0, stream>>>(
                W2 + wF2 + (size_t)c * 2048 * DMODEL, wt, 2048, DMODEL, DMODEL);
            mfma_gemm<float><<<gG_n1, blk, 0, stream>>>(
                big, wt, (c == 0) ? (b2 + vD) : nullptr, h, h,
                M_ROWS, DMODEL, 2048, 0);
        }
    }

    ln_kernel<float><<<M_ROWS, blk, 0, stream>>>(h, lnf_s, lnf_b, (float*)d_out);
}

// Round 5
// 2303.912 us; speedup vs baseline: 3.7485x; 1.1157x over previous
//
#include <hip/hip_runtime.h>
#include <hip/hip_bf16.h>
#include <math.h>

typedef __hip_bfloat16 bf16;
typedef __attribute__((ext_vector_type(8))) short short8;
typedef __attribute__((ext_vector_type(4))) float f32x4;

#define S_LEN 1024
#define BATCH 4
#define M_ROWS 4096
#define DMODEL 1024
#define DFF 4096
#define NHEAD 8
#define DHEAD 128
#define WIN 100
#define LFWD 20

__device__ __forceinline__ void gl_lds16(const void* g, void* l) {
    __builtin_amdgcn_global_load_lds(
        (const __attribute__((address_space(1))) void*)g,
        (__attribute__((address_space(3))) void*)l, 16, 0, 0);
}

__device__ __forceinline__ float bf2f(unsigned short u) {
    return __uint_as_float(((unsigned)u) << 16);
}

// ---------------- MFMA GEMM: C = act(A @ Bt^T + bias) (+resid) ----------------
// A: M x K bf16 row-major. Bt: N x K bf16 (W^T). bias fp32 (nullable),
// resid fp32 M x N (nullable), C: M x N (TC). Tile 128x128, BK=32.
template<typename TC>
__global__ __launch_bounds__(256)
void mfma_gemm(const bf16* __restrict__ A, const bf16* __restrict__ Bt,
               const float* __restrict__ bias, TC* __restrict__ C,
               const float* __restrict__ resid, int M, int N, int K, int act)
{
    __shared__ bf16 As[128 * 32];
    __shared__ bf16 Bs[128 * 32];
    const int bm = blockIdx.y * 128;
    const int bn = blockIdx.x * 128;
    const int tid = threadIdx.x;
    const int w = tid >> 6, lane = tid & 63;
    const int wm = (w & 1) * 64, wn = (w >> 1) * 64;

    const int srow = w * 32 + (lane >> 2);
    const int selem = (lane & 3) * 8;
    const bf16* ga0 = A + (size_t)(bm + srow) * K + selem;
    const bf16* ga1 = ga0 + (size_t)16 * K;
    const bf16* gb0 = Bt + (size_t)(bn + srow) * K + selem;
    const bf16* gb1 = gb0 + (size_t)16 * K;
    bf16* la0 = As + (w * 32) * 32;
    bf16* la1 = As + (w * 32 + 16) * 32;
    bf16* lb0 = Bs + (w * 32) * 32;
    bf16* lb1 = Bs + (w * 32 + 16) * 32;

    f32x4 acc[4][4] = {};
    const int koff = (lane >> 4) * 8;
    const int fr = lane & 15;

    for (int k0 = 0; k0 < K; k0 += 32) {
        gl_lds16(ga0, la0); gl_lds16(ga1, la1);
        gl_lds16(gb0, lb0); gl_lds16(gb1, lb1);
        ga0 += 32; ga1 += 32; gb0 += 32; gb1 += 32;
        __syncthreads();
        short8 af[4], bfr[4];
#pragma unroll
        for (int i = 0; i < 4; ++i)
            af[i] = *(const short8*)(As + (wm + i * 16 + fr) * 32 + koff);
#pragma unroll
        for (int j = 0; j < 4; ++j)
            bfr[j] = *(const short8*)(Bs + (wn + j * 16 + fr) * 32 + koff);
#pragma unroll
        for (int i = 0; i < 4; ++i)
#pragma unroll
            for (int j = 0; j < 4; ++j)
                acc[i][j] = __builtin_amdgcn_mfma_f32_16x16x32_bf16(
                    af[i], bfr[j], acc[i][j], 0, 0, 0);
        __syncthreads();
    }

    const int cq = lane >> 4, cn = lane & 15;
#pragma unroll
    for (int i = 0; i < 4; ++i) {
#pragma unroll
        for (int r = 0; r < 4; ++r) {
            int row = bm + wm + i * 16 + cq * 4 + r;
#pragma unroll
            for (int j = 0; j < 4; ++j) {
                int col = bn + wn + j * 16 + cn;
                float v = acc[i][j][r];
                if (bias) v += bias[col];
                if (act)  v = v / (1.0f + __expf(-v));   // silu
                if (resid) v += resid[(size_t)row * N + col];
                C[(size_t)row * N + col] = (TC)v;
            }
        }
    }
}

// -------- transpose+cast: W (K x N fp32, row stride ld) -> Wt (N x K bf16) --------
__global__ void transpose_kernel(const float* __restrict__ W, bf16* __restrict__ Wt,
                                 int K, int N, int ld)
{
    __shared__ float t[32][33];
    const int n0 = blockIdx.x * 32, k0 = blockIdx.y * 32;
    const int tx = threadIdx.x & 31, ty = threadIdx.x >> 5;
#pragma unroll
    for (int i = 0; i < 32; i += 8)
        t[ty + i][tx] = W[(size_t)(k0 + ty + i) * ld + n0 + tx];
    __syncthreads();
#pragma unroll
    for (int i = 0; i < 32; i += 8)
        Wt[(size_t)(n0 + ty + i) * K + k0 + tx] = (bf16)t[tx][ty + i];
}

// ---------------- fp32 -> bf16 convert ----------------
__global__ void cvt_kernel(const float* __restrict__ s, bf16* __restrict__ d)
{
    size_t i = ((size_t)blockIdx.x * 256 + threadIdx.x) * 4;
    float4 v = *(const float4*)(s + i);
    d[i] = (bf16)v.x; d[i + 1] = (bf16)v.y; d[i + 2] = (bf16)v.z; d[i + 3] = (bf16)v.w;
}

// ---------------- concat 3 bias vectors of 1024 fp32 ----------------
__global__ void concat3_kernel(const float* __restrict__ a, const float* __restrict__ b,
                               const float* __restrict__ c, float* __restrict__ o)
{
    int i = blockIdx.x * 256 + threadIdx.x;   // 0..3071
    o[i] = (i < 1024) ? a[i] : (i < 2048 ? b[i - 1024] : c[i - 2048]);
}

// ---------------- zero padded rows of h ----------------
__global__ void pad_kernel(float* __restrict__ h, const int* __restrict__ xlen)
{
    int row = blockIdx.x;
    int b = row >> 10, s = row & 1023;
    int len = xlen[b] >> 2;
    if (s < len) return;
    for (int d = threadIdx.x; d < DMODEL; d += 256)
        h[(size_t)row * DMODEL + d] = 0.0f;
}

// ---------------- LayerNorm (row of 1024), fp32 in, TO out ----------------
template<typename TO>
__global__ void ln_kernel(const float* __restrict__ x, const float* __restrict__ sc,
                          const float* __restrict__ bi, TO* __restrict__ y)
{
    int row = blockIdx.x;
    const float* xr = x + (size_t)row * DMODEL;
    float vals[4];
    float lsum = 0.0f, lsq = 0.0f;
#pragma unroll
    for (int t = 0; t < 4; ++t) {
        float v = xr[threadIdx.x + 256 * t];
        vals[t] = v; lsum += v; lsq += v * v;
    }
    for (int o = 32; o > 0; o >>= 1) {
        lsum += __shfl_down(lsum, o, 64);
        lsq  += __shfl_down(lsq,  o, 64);
    }
    __shared__ float s1[4], s2[4];
    int wv = threadIdx.x >> 6, ln = threadIdx.x & 63;
    if (ln == 0) { s1[wv] = lsum; s2[wv] = lsq; }
    __syncthreads();
    if (threadIdx.x == 0) {
        float a = s1[0] + s1[1] + s1[2] + s1[3];
        float b = s2[0] + s2[1] + s2[2] + s2[3];
        float mu = a * (1.0f / DMODEL);
        float var = b * (1.0f / DMODEL) - mu * mu;
        s1[0] = mu;
        s2[0] = rsqrtf(fmaxf(var, 0.0f) + 1e-5f);
    }
    __syncthreads();
    float mu = s1[0], inv = s2[0];
#pragma unroll
    for (int t = 0; t < 4; ++t) {
        int d = threadIdx.x + 256 * t;
        y[(size_t)row * DMODEL + d] = (TO)((vals[t] - mu) * inv * sc[d] + bi[d]);
    }
}

// ---------------- RoPE (in-place, bf16, strided) ----------------
__global__ void rope_kernel(bf16* __restrict__ q, bf16* __restrict__ k, int stride)
{
    size_t idx = (size_t)blockIdx.x * 256 + threadIdx.x;  // over B*S*H*64
    int d = idx & 63;
    size_t rest = idx >> 6;
    int hh = rest & 7;
    int s = (rest >> 3) & 1023;
    size_t base = (rest >> 3) * stride + (size_t)hh * DHEAD;
    float inv = powf(10000.0f, -(float)d / 64.0f);
    float ang = (float)s * inv;
    float c = cosf(ang), si = sinf(ang);
    {
        float x1 = (float)q[base + d], x2 = (float)q[base + 64 + d];
        q[base + d]      = (bf16)(x1 * c - x2 * si);
        q[base + 64 + d] = (bf16)(x1 * si + x2 * c);
    }
    {
        float x1 = (float)k[base + d], x2 = (float)k[base + 64 + d];
        k[base + d]      = (bf16)(x1 * c - x2 * si);
        k[base + 64 + d] = (bf16)(x1 * si + x2 * c);
    }
}

// ---------------- mean of v over all s, per (b,h) ----------------
__global__ void vmean_kernel(const bf16* __restrict__ v, float* __restrict__ vmean,
                             int stride)
{
    int bh = blockIdx.x;
    int b = bh >> 3, hh = bh & 7;
    int d = threadIdx.x;  // 128
    float acc = 0.0f;
    for (int s = 0; s < S_LEN; ++s)
        acc += (float)v[((size_t)(b * S_LEN + s)) * stride + hh * DHEAD + d];
    vmean[(size_t)bh * DHEAD + d] = acc * (1.0f / S_LEN);
}

// ---------------- windowed attention, one wave per (b,h,i) ----------------
__global__ void attn_kernel(const bf16* __restrict__ q, const bf16* __restrict__ k,
                            const bf16* __restrict__ v, const float* __restrict__ vmean,
                            const int* __restrict__ xlen, bf16* __restrict__ ctx,
                            int stride)
{
    const int lane = threadIdx.x;  // 64
    int bhi = blockIdx.x;
    int i = bhi & 1023;
    int hh = (bhi >> 10) & 7;
    int b = bhi >> 13;
    int len = xlen[b] >> 2;
    size_t rowQ = ((size_t)(b * S_LEN + i)) * stride + hh * DHEAD;
    size_t rowC = ((size_t)(b * S_LEN + i)) * DMODEL + hh * DHEAD;
    int j0 = i - (WIN - 1); if (j0 < 0) j0 = 0;
    if (j0 >= len) {
        const float* vm = vmean + (size_t)(b * NHEAD + hh) * DHEAD;
        ctx[rowC + 2 * lane]     = (bf16)vm[2 * lane];
        ctx[rowC + 2 * lane + 1] = (bf16)vm[2 * lane + 1];
        return;
    }
    int j1 = i + LFWD; if (j1 > S_LEN - 1) j1 = S_LEN - 1;
    if (j1 > len - 1) j1 = len - 1;

    __shared__ float qs[DHEAD];
    __shared__ float p[128];
    qs[lane]      = (float)q[rowQ + lane];
    qs[lane + 64] = (float)q[rowQ + 64 + lane];
    __syncthreads();

    const float scale = 0.088388347648318447f;  // 1/sqrt(128)
    int jA = j0 + lane, jB = j0 + 64 + lane;
    float s0 = -1e30f, s1 = -1e30f;
    if (jA <= j1) {
        const short8* kr = (const short8*)(k + ((size_t)(b * S_LEN + jA)) * stride + hh * DHEAD);
        float acc = 0.0f;
#pragma unroll
        for (int c = 0; c < 16; ++c) {
            short8 kk = kr[c];
#pragma unroll
            for (int t = 0; t < 8; ++t)
                acc += qs[c * 8 + t] * bf2f((unsigned short)kk[t]);
        }
        s0 = acc * scale;
    }
    if (jB <= j1) {
        const short8* kr = (const short8*)(k + ((size_t)(b * S_LEN + jB)) * stride + hh * DHEAD);
        float acc = 0.0f;
#pragma unroll
        for (int c = 0; c < 16; ++c) {
            short8 kk = kr[c];
#pragma unroll
            for (int t = 0; t < 8; ++t)
                acc += qs[c * 8 + t] * bf2f((unsigned short)kk[t]);
        }
        s1 = acc * scale;
    }
    float m = fmaxf(s0, s1);
    for (int o = 32; o > 0; o >>= 1) m = fmaxf(m, __shfl_down(m, o, 64));
    m = __shfl(m, 0, 64);
    float e0 = (jA <= j1) ? __expf(s0 - m) : 0.0f;
    float e1 = (jB <= j1) ? __expf(s1 - m) : 0.0f;
    float ssum = e0 + e1;
    for (int o = 32; o > 0; o >>= 1) ssum += __shfl_down(ssum, o, 64);
    ssum = __shfl(ssum, 0, 64);
    float inv = 1.0f / fmaxf(ssum, 1e-30f);
    p[lane] = e0 * inv;
    p[lane + 64] = e1 * inv;
    __syncthreads();

    // PV: lane owns d = 2*lane, 2*lane+1; one coalesced 4B load per key row
    float a0 = 0.0f, a1 = 0.0f;
    for (int j = j0; j <= j1; ++j) {
        float pj = p[j - j0];
        const unsigned* vr = (const unsigned*)(v + ((size_t)(b * S_LEN + j)) * stride + hh * DHEAD);
        unsigned u = vr[lane];
        a0 += pj * bf2f((unsigned short)(u & 0xffff));
        a1 += pj * bf2f((unsigned short)(u >> 16));
    }
    ctx[rowC + 2 * lane]     = (bf16)a0;
    ctx[rowC + 2 * lane + 1] = (bf16)a1;
}

extern "C" void kernel_launch(void* const* d_in, const int* in_sizes, int n_in,
                              void* d_out, int out_size, void* d_ws, size_t ws_size,
                              hipStream_t stream)
{
    const float* x      = (const float*)d_in[0];
    const int*   xlen   = (const int*)d_in[1];
    const float* Wp     = (const float*)d_in[2];
    const float* bp     = (const float*)d_in[3];
    const float* ln1_s  = (const float*)d_in[4];
    const float* ln1_b  = (const float*)d_in[5];
    const float* Wq     = (const float*)d_in[6];
    const float* bq     = (const float*)d_in[7];
    const float* Wk     = (const float*)d_in[8];
    const float* bk     = (const float*)d_in[9];
    const float* Wv     = (const float*)d_in[10];
    const float* bv     = (const float*)d_in[11];
    const float* Wo     = (const float*)d_in[12];
    const float* bo     = (const float*)d_in[13];
    const float* ln2_s  = (const float*)d_in[14];
    const float* ln2_b  = (const float*)d_in[15];
    const float* W1     = (const float*)d_in[16];
    const float* b1     = (const float*)d_in[17];
    const float* W2     = (const float*)d_in[18];
    const float* b2     = (const float*)d_in[19];
    const float* lnf_s  = (const float*)d_in[20];
    const float* lnf_b  = (const float*)d_in[21];
    (void)in_sizes; (void)n_in; (void)out_size; (void)ws_size;

    // ---- workspace: 56 MB + ~28 KB ----
    const size_t MD = (size_t)M_ROWS * DMODEL;            // 4M elems
    float* h     = (float*)d_ws;                          // [0,16) MB
    bf16*  y     = (bf16*)(h + MD);                       // [16,24) MB
    bf16*  U     = y + MD;                                // [24,56) MB union
    bf16*  xb    = U;                                     // 16 MB (proj input)
    bf16*  qkv   = U;                                     // 24 MB, stride 3072
    bf16*  mid   = U;                                     // 32 MB (FFN mid)
    float* vmean = (float*)(U + 16 * 1024 * 1024);        // 56 MB + 16 KB
    float* bqkv  = vmean + BATCH * NHEAD * DHEAD;         // 12 KB
    // d_out (16 MB fp32) is scratch until final LN:
    bf16*  wt    = (bf16*)d_out;                          // up to 8 MB

    const int QS = 3 * DMODEL;   // qkv row stride

    dim3 blk(256);
    dim3 gG_n1(DMODEL / 128, M_ROWS / 128);               // 256 blocks

    // xb = bf16(x); h = xb @ Wp^T + bp; pad
    cvt_kernel<<<(2 * MD) / (256 * 4), blk, 0, stream>>>(x, xb);
    transpose_kernel<<<dim3(DMODEL / 32, 2048 / 32), blk, 0, stream>>>(Wp, wt, 2048, DMODEL, DMODEL);
    mfma_gemm<float><<<gG_n1, blk, 0, stream>>>(xb, wt, bp, h, nullptr,
                                                M_ROWS, DMODEL, 2048, 0);
    pad_kernel<<<M_ROWS, blk, 0, stream>>>(h, xlen);

    for (int l = 0; l < 4; ++l) {
        const size_t wD  = (size_t)l * DMODEL * DMODEL;
        const size_t wF  = (size_t)l * DMODEL * DFF;   // W1 (1024 x 4096)
        const size_t wF2 = (size_t)l * DFF * DMODEL;   // W2 (4096 x 1024)
        const size_t vD  = (size_t)l * DMODEL;
        const size_t vF  = (size_t)l * DFF;
        const size_t W1T_ELEMS = (size_t)DFF * DMODEL; // 4M

        ln_kernel<bf16><<<M_ROWS, blk, 0, stream>>>(h, ln1_s + vD, ln1_b + vD, y);

        // fused QKV: wt = [Wq^T; Wk^T; Wv^T] (3072 x 1024), qkv = y @ wt^T + [bq;bk;bv]
        transpose_kernel<<<dim3(32, 32), blk, 0, stream>>>(Wq + wD, wt, DMODEL, DMODEL, DMODEL);
        transpose_kernel<<<dim3(32, 32), blk, 0, stream>>>(Wk + wD, wt + MD / 4, DMODEL, DMODEL, DMODEL);
        transpose_kernel<<<dim3(32, 32), blk, 0, stream>>>(Wv + wD, wt + MD / 2, DMODEL, DMODEL, DMODEL);
        concat3_kernel<<<12, blk, 0, stream>>>(bq + vD, bk + vD, bv + vD, bqkv);
        mfma_gemm<bf16><<<dim3(3 * DMODEL / 128, M_ROWS / 128), blk, 0, stream>>>(
            y, wt, bqkv, qkv, nullptr, M_ROWS, 3 * DMODEL, DMODEL, 0);

        bf16* qb = qkv;
        bf16* kb = qkv + DMODEL;
        bf16* vb = qkv + 2 * DMODEL;
        rope_kernel<<<(M_ROWS * NHEAD * 64) / 256, blk, 0, stream>>>(qb, kb, QS);
        vmean_kernel<<<BATCH * NHEAD, dim3(DHEAD), 0, stream>>>(vb, vmean, QS);
        attn_kernel<<<BATCH * NHEAD * S_LEN, dim3(64), 0, stream>>>(qb, kb, vb, vmean,
                                                                    xlen, y, QS);

        transpose_kernel<<<dim3(32, 32), blk, 0, stream>>>(Wo + wD, wt, DMODEL, DMODEL, DMODEL);
        mfma_gemm<float><<<gG_n1, blk, 0, stream>>>(y, wt, bo + vD, h, h,
                                                    M_ROWS, DMODEL, DMODEL, 0);

        ln_kernel<bf16><<<M_ROWS, blk, 0, stream>>>(h, ln2_s + vD, ln2_b + vD, y);

        // FFN1 full width: mid = silu(y @ W1^T + b1)   (1024 blocks)
        transpose_kernel<<<dim3(DFF / 32, DMODEL / 32), blk, 0, stream>>>(
            W1 + wF, wt, DMODEL, DFF, DFF);
        mfma_gemm<bf16><<<dim3(DFF / 128, M_ROWS / 128), blk, 0, stream>>>(
            y, wt, b1 + vF, mid, nullptr, M_ROWS, DFF, DMODEL, 1);
        // FFN2: h = h + mid @ W2^T + b2
        transpose_kernel<<<dim3(DMODEL / 32, DFF / 32), blk, 0, stream>>>(
            W2 + wF2, wt, DFF, DMODEL, DMODEL);
        mfma_gemm<float><<<gG_n1, blk, 0, stream>>>(
            mid, wt, b2 + vD, h, h, M_ROWS, DMODEL, DFF, 0);
    }

    ln_kernel<float><<<M_ROWS, blk, 0, stream>>>(h, lnf_s, lnf_b, (float*)d_out);
}

// Round 6
// 2069.156 us; speedup vs baseline: 4.1738x; 1.1135x over previous
//
#include <hip/hip_runtime.h>
#include <hip/hip_bf16.h>
#include <math.h>

typedef __hip_bfloat16 bf16;
typedef __attribute__((ext_vector_type(8))) short short8;
typedef __attribute__((ext_vector_type(4))) float f32x4;

#define S_LEN 1024
#define BATCH 4
#define M_ROWS 4096
#define DMODEL 1024
#define DFF 4096
#define NHEAD 8
#define DHEAD 128
#define WIN 100
#define LFWD 20

__device__ __forceinline__ void gl_lds16(const void* g, void* l) {
    __builtin_amdgcn_global_load_lds(
        (const __attribute__((address_space(1))) void*)g,
        (__attribute__((address_space(3))) void*)l, 16, 0, 0);
}

__device__ __forceinline__ float bf2f(unsigned short u) {
    return __uint_as_float(((unsigned)u) << 16);
}

// ---------------- MFMA GEMM (no split): C = act(A @ Bt^T + bias) ----------------
template<typename TC>
__global__ __launch_bounds__(256)
void mfma_gemm(const bf16* __restrict__ A, const bf16* __restrict__ Bt,
               const float* __restrict__ bias, TC* __restrict__ C,
               int M, int N, int K, int act)
{
    __shared__ bf16 As[128 * 32];
    __shared__ bf16 Bs[128 * 32];
    const int bm = blockIdx.y * 128;
    const int bn = blockIdx.x * 128;
    const int tid = threadIdx.x;
    const int w = tid >> 6, lane = tid & 63;
    const int wm = (w & 1) * 64, wn = (w >> 1) * 64;

    const int srow = w * 32 + (lane >> 2);
    const int selem = (lane & 3) * 8;
    const bf16* ga0 = A + (size_t)(bm + srow) * K + selem;
    const bf16* ga1 = ga0 + (size_t)16 * K;
    const bf16* gb0 = Bt + (size_t)(bn + srow) * K + selem;
    const bf16* gb1 = gb0 + (size_t)16 * K;
    bf16* la0 = As + (w * 32) * 32;
    bf16* la1 = As + (w * 32 + 16) * 32;
    bf16* lb0 = Bs + (w * 32) * 32;
    bf16* lb1 = Bs + (w * 32 + 16) * 32;

    f32x4 acc[4][4] = {};
    const int koff = (lane >> 4) * 8;
    const int fr = lane & 15;

    for (int k0 = 0; k0 < K; k0 += 32) {
        gl_lds16(ga0, la0); gl_lds16(ga1, la1);
        gl_lds16(gb0, lb0); gl_lds16(gb1, lb1);
        ga0 += 32; ga1 += 32; gb0 += 32; gb1 += 32;
        __syncthreads();
        short8 af[4], bfr[4];
#pragma unroll
        for (int i = 0; i < 4; ++i)
            af[i] = *(const short8*)(As + (wm + i * 16 + fr) * 32 + koff);
#pragma unroll
        for (int j = 0; j < 4; ++j)
            bfr[j] = *(const short8*)(Bs + (wn + j * 16 + fr) * 32 + koff);
#pragma unroll
        for (int i = 0; i < 4; ++i)
#pragma unroll
            for (int j = 0; j < 4; ++j)
                acc[i][j] = __builtin_amdgcn_mfma_f32_16x16x32_bf16(
                    af[i], bfr[j], acc[i][j], 0, 0, 0);
        __syncthreads();
    }

    const int cq = lane >> 4, cn = lane & 15;
#pragma unroll
    for (int i = 0; i < 4; ++i) {
#pragma unroll
        for (int r = 0; r < 4; ++r) {
            int row = bm + wm + i * 16 + cq * 4 + r;
#pragma unroll
            for (int j = 0; j < 4; ++j) {
                int col = bn + wn + j * 16 + cn;
                float v = acc[i][j][r] + bias[col];
                if (act) v = v / (1.0f + __expf(-v));   // silu
                C[(size_t)row * N + col] = (TC)v;
            }
        }
    }
}

// ---------- MFMA GEMM split-K=2: z=0 -> C=acc+bias(+resid), z=1 -> P=acc ----------
// P is split: rows < prows0 go to P0, rest to P1 (both fp32, stride N).
__global__ __launch_bounds__(256)
void mfma_gemm_sk(const bf16* __restrict__ A, const bf16* __restrict__ Bt,
                  const float* __restrict__ bias, float* __restrict__ C,
                  const float* __restrict__ resid,
                  float* __restrict__ P0, float* __restrict__ P1, int prows0,
                  int M, int N, int K)
{
    __shared__ bf16 As[128 * 32];
    __shared__ bf16 Bs[128 * 32];
    const int bm = blockIdx.y * 128;
    const int bn = blockIdx.x * 128;
    const int z = blockIdx.z;
    const int khalf = K >> 1;
    const int kstart = z * khalf;
    const int tid = threadIdx.x;
    const int w = tid >> 6, lane = tid & 63;
    const int wm = (w & 1) * 64, wn = (w >> 1) * 64;

    const int srow = w * 32 + (lane >> 2);
    const int selem = (lane & 3) * 8;
    const bf16* ga0 = A + (size_t)(bm + srow) * K + kstart + selem;
    const bf16* ga1 = ga0 + (size_t)16 * K;
    const bf16* gb0 = Bt + (size_t)(bn + srow) * K + kstart + selem;
    const bf16* gb1 = gb0 + (size_t)16 * K;
    bf16* la0 = As + (w * 32) * 32;
    bf16* la1 = As + (w * 32 + 16) * 32;
    bf16* lb0 = Bs + (w * 32) * 32;
    bf16* lb1 = Bs + (w * 32 + 16) * 32;

    f32x4 acc[4][4] = {};
    const int koff = (lane >> 4) * 8;
    const int fr = lane & 15;

    for (int k0 = 0; k0 < khalf; k0 += 32) {
        gl_lds16(ga0, la0); gl_lds16(ga1, la1);
        gl_lds16(gb0, lb0); gl_lds16(gb1, lb1);
        ga0 += 32; ga1 += 32; gb0 += 32; gb1 += 32;
        __syncthreads();
        short8 af[4], bfr[4];
#pragma unroll
        for (int i = 0; i < 4; ++i)
            af[i] = *(const short8*)(As + (wm + i * 16 + fr) * 32 + koff);
#pragma unroll
        for (int j = 0; j < 4; ++j)
            bfr[j] = *(const short8*)(Bs + (wn + j * 16 + fr) * 32 + koff);
#pragma unroll
        for (int i = 0; i < 4; ++i)
#pragma unroll
            for (int j = 0; j < 4; ++j)
                acc[i][j] = __builtin_amdgcn_mfma_f32_16x16x32_bf16(
                    af[i], bfr[j], acc[i][j], 0, 0, 0);
        __syncthreads();
    }

    const int cq = lane >> 4, cn = lane & 15;
#pragma unroll
    for (int i = 0; i < 4; ++i) {
#pragma unroll
        for (int r = 0; r < 4; ++r) {
            int row = bm + wm + i * 16 + cq * 4 + r;
#pragma unroll
            for (int j = 0; j < 4; ++j) {
                int col = bn + wn + j * 16 + cn;
                float v = acc[i][j][r];
                if (z == 0) {
                    v += bias[col];
                    if (resid) v += resid[(size_t)row * N + col];
                    C[(size_t)row * N + col] = v;
                } else {
                    float* P = (row < prows0) ? (P0 + (size_t)row * N + col)
                                              : (P1 + (size_t)(row - prows0) * N + col);
                    *P = v;
                }
            }
        }
    }
}

// -------- transpose+cast: W (K x N fp32, row stride ld) -> Wt (N x K bf16) --------
__global__ void transpose_kernel(const float* __restrict__ W, bf16* __restrict__ Wt,
                                 int K, int N, int ld)
{
    __shared__ float t[32][33];
    const int n0 = blockIdx.x * 32, k0 = blockIdx.y * 32;
    const int tx = threadIdx.x & 31, ty = threadIdx.x >> 5;
#pragma unroll
    for (int i = 0; i < 32; i += 8)
        t[ty + i][tx] = W[(size_t)(k0 + ty + i) * ld + n0 + tx];
    __syncthreads();
#pragma unroll
    for (int i = 0; i < 32; i += 8)
        Wt[(size_t)(n0 + ty + i) * K + k0 + tx] = (bf16)t[tx][ty + i];
}

// ---------------- fp32 -> bf16 convert ----------------
__global__ void cvt_kernel(const float* __restrict__ s, bf16* __restrict__ d)
{
    size_t i = ((size_t)blockIdx.x * 256 + threadIdx.x) * 4;
    float4 v = *(const float4*)(s + i);
    d[i] = (bf16)v.x; d[i + 1] = (bf16)v.y; d[i + 2] = (bf16)v.z; d[i + 3] = (bf16)v.w;
}

// ---------------- concat 3 bias vectors of 1024 fp32 ----------------
__global__ void concat3_kernel(const float* __restrict__ a, const float* __restrict__ b,
                               const float* __restrict__ c, float* __restrict__ o)
{
    int i = blockIdx.x * 256 + threadIdx.x;   // 0..3071
    o[i] = (i < 1024) ? a[i] : (i < 2048 ? b[i - 1024] : c[i - 2048]);
}

// ---------------- h = pad ? 0 : h + P ----------------
__global__ void pad_red_kernel(float* __restrict__ h, const float* __restrict__ P,
                               const int* __restrict__ xlen)
{
    int row = blockIdx.x;
    int b = row >> 10, s = row & 1023;
    int len = xlen[b] >> 2;
    size_t off = (size_t)row * DMODEL;
    if (s >= len) {
        for (int d = threadIdx.x; d < DMODEL; d += 256) h[off + d] = 0.0f;
    } else {
        for (int d = threadIdx.x; d < DMODEL; d += 256) h[off + d] += P[off + d];
    }
}

// ---------------- h += P (split P0/P1) ----------------
__global__ void reduce2_kernel(float* __restrict__ h, const float* __restrict__ P0,
                               const float* __restrict__ P1, int prows0)
{
    int row = blockIdx.x;
    const float* P = (row < prows0) ? (P0 + (size_t)row * DMODEL)
                                    : (P1 + (size_t)(row - prows0) * DMODEL);
    size_t off = (size_t)row * DMODEL;
#pragma unroll
    for (int t = 0; t < 4; ++t) {
        int d = threadIdx.x + 256 * t;
        h[off + d] += P[d];
    }
}

// ---------------- LayerNorm (row of 1024), fp32 in, TO out; optional P fold ------
template<typename TO, bool RED>
__global__ void ln_kernel(float* __restrict__ x, const float* __restrict__ P0,
                          const float* __restrict__ sc, const float* __restrict__ bi,
                          TO* __restrict__ y)
{
    int row = blockIdx.x;
    float* xr = x + (size_t)row * DMODEL;
    const float* pr = RED ? (P0 + (size_t)row * DMODEL) : nullptr;
    float vals[4];
    float lsum = 0.0f, lsq = 0.0f;
#pragma unroll
    for (int t = 0; t < 4; ++t) {
        int d = threadIdx.x + 256 * t;
        float v = xr[d];
        if (RED) { v += pr[d]; xr[d] = v; }
        vals[t] = v; lsum += v; lsq += v * v;
    }
    for (int o = 32; o > 0; o >>= 1) {
        lsum += __shfl_down(lsum, o, 64);
        lsq  += __shfl_down(lsq,  o, 64);
    }
    __shared__ float s1[4], s2[4];
    int wv = threadIdx.x >> 6, ln = threadIdx.x & 63;
    if (ln == 0) { s1[wv] = lsum; s2[wv] = lsq; }
    __syncthreads();
    if (threadIdx.x == 0) {
        float a = s1[0] + s1[1] + s1[2] + s1[3];
        float b = s2[0] + s2[1] + s2[2] + s2[3];
        float mu = a * (1.0f / DMODEL);
        float var = b * (1.0f / DMODEL) - mu * mu;
        s1[0] = mu;
        s2[0] = rsqrtf(fmaxf(var, 0.0f) + 1e-5f);
    }
    __syncthreads();
    float mu = s1[0], inv = s2[0];
#pragma unroll
    for (int t = 0; t < 4; ++t) {
        int d = threadIdx.x + 256 * t;
        y[(size_t)row * DMODEL + d] = (TO)((vals[t] - mu) * inv * sc[d] + bi[d]);
    }
}

// ---------------- RoPE (in-place, bf16, strided) ----------------
__global__ void rope_kernel(bf16* __restrict__ q, bf16* __restrict__ k, int stride)
{
    size_t idx = (size_t)blockIdx.x * 256 + threadIdx.x;
    int d = idx & 63;
    size_t rest = idx >> 6;
    int hh = rest & 7;
    int s = (rest >> 3) & 1023;
    size_t base = (rest >> 3) * stride + (size_t)hh * DHEAD;
    float inv = powf(10000.0f, -(float)d / 64.0f);
    float ang = (float)s * inv;
    float c = cosf(ang), si = sinf(ang);
    {
        float x1 = (float)q[base + d], x2 = (float)q[base + 64 + d];
        q[base + d]      = (bf16)(x1 * c - x2 * si);
        q[base + 64 + d] = (bf16)(x1 * si + x2 * c);
    }
    {
        float x1 = (float)k[base + d], x2 = (float)k[base + 64 + d];
        k[base + d]      = (bf16)(x1 * c - x2 * si);
        k[base + 64 + d] = (bf16)(x1 * si + x2 * c);
    }
}

// ---------------- mean of v over all s, per (b,h) ----------------
__global__ void vmean_kernel(const bf16* __restrict__ v, float* __restrict__ vmean,
                             int stride)
{
    int bh = blockIdx.x;
    int b = bh >> 3, hh = bh & 7;
    int d = threadIdx.x;  // 128
    float acc = 0.0f;
    for (int s = 0; s < S_LEN; ++s)
        acc += (float)v[((size_t)(b * S_LEN + s)) * stride + hh * DHEAD + d];
    vmean[(size_t)bh * DHEAD + d] = acc * (1.0f / S_LEN);
}

// ---------------- windowed attention, one wave per (b,h,i) ----------------
__global__ void attn_kernel(const bf16* __restrict__ q, const bf16* __restrict__ k,
                            const bf16* __restrict__ v, const float* __restrict__ vmean,
                            const int* __restrict__ xlen, bf16* __restrict__ ctx,
                            int stride)
{
    const int lane = threadIdx.x;  // 64
    int bhi = blockIdx.x;
    int i = bhi & 1023;
    int hh = (bhi >> 10) & 7;
    int b = bhi >> 13;
    int len = xlen[b] >> 2;
    size_t rowQ = ((size_t)(b * S_LEN + i)) * stride + hh * DHEAD;
    size_t rowC = ((size_t)(b * S_LEN + i)) * DMODEL + hh * DHEAD;
    int j0 = i - (WIN - 1); if (j0 < 0) j0 = 0;
    if (j0 >= len) {
        const float* vm = vmean + (size_t)(b * NHEAD + hh) * DHEAD;
        ctx[rowC + 2 * lane]     = (bf16)vm[2 * lane];
        ctx[rowC + 2 * lane + 1] = (bf16)vm[2 * lane + 1];
        return;
    }
    int j1 = i + LFWD; if (j1 > S_LEN - 1) j1 = S_LEN - 1;
    if (j1 > len - 1) j1 = len - 1;

    __shared__ float qs[DHEAD];
    __shared__ float p[128];
    qs[lane]      = (float)q[rowQ + lane];
    qs[lane + 64] = (float)q[rowQ + 64 + lane];
    __syncthreads();

    const float scale = 0.088388347648318447f;  // 1/sqrt(128)
    int jA = j0 + lane, jB = j0 + 64 + lane;
    float s0 = -1e30f, s1 = -1e30f;
    if (jA <= j1) {
        const short8* kr = (const short8*)(k + ((size_t)(b * S_LEN + jA)) * stride + hh * DHEAD);
        float acc = 0.0f;
#pragma unroll
        for (int c = 0; c < 16; ++c) {
            short8 kk = kr[c];
#pragma unroll
            for (int t = 0; t < 8; ++t)
                acc += qs[c * 8 + t] * bf2f((unsigned short)kk[t]);
        }
        s0 = acc * scale;
    }
    if (jB <= j1) {
        const short8* kr = (const short8*)(k + ((size_t)(b * S_LEN + jB)) * stride + hh * DHEAD);
        float acc = 0.0f;
#pragma unroll
        for (int c = 0; c < 16; ++c) {
            short8 kk = kr[c];
#pragma unroll
            for (int t = 0; t < 8; ++t)
                acc += qs[c * 8 + t] * bf2f((unsigned short)kk[t]);
        }
        s1 = acc * scale;
    }
    float m = fmaxf(s0, s1);
    for (int o = 32; o > 0; o >>= 1) m = fmaxf(m, __shfl_down(m, o, 64));
    m = __shfl(m, 0, 64);
    float e0 = (jA <= j1) ? __expf(s0 - m) : 0.0f;
    float e1 = (jB <= j1) ? __expf(s1 - m) : 0.0f;
    float ssum = e0 + e1;
    for (int o = 32; o > 0; o >>= 1) ssum += __shfl_down(ssum, o, 64);
    ssum = __shfl(ssum, 0, 64);
    float inv = 1.0f / fmaxf(ssum, 1e-30f);
    p[lane] = e0 * inv;
    p[lane + 64] = e1 * inv;
    __syncthreads();

    float a0 = 0.0f, a1 = 0.0f;
    for (int j = j0; j <= j1; ++j) {
        float pj = p[j - j0];
        const unsigned* vr = (const unsigned*)(v + ((size_t)(b * S_LEN + j)) * stride + hh * DHEAD);
        unsigned u = vr[lane];
        a0 += pj * bf2f((unsigned short)(u & 0xffff));
        a1 += pj * bf2f((unsigned short)(u >> 16));
    }
    ctx[rowC + 2 * lane]     = (bf16)a0;
    ctx[rowC + 2 * lane + 1] = (bf16)a1;
}

extern "C" void kernel_launch(void* const* d_in, const int* in_sizes, int n_in,
                              void* d_out, int out_size, void* d_ws, size_t ws_size,
                              hipStream_t stream)
{
    const float* x      = (const float*)d_in[0];
    const int*   xlen   = (const int*)d_in[1];
    const float* Wp     = (const float*)d_in[2];
    const float* bp     = (const float*)d_in[3];
    const float* ln1_s  = (const float*)d_in[4];
    const float* ln1_b  = (const float*)d_in[5];
    const float* Wq     = (const float*)d_in[6];
    const float* bq     = (const float*)d_in[7];
    const float* Wk     = (const float*)d_in[8];
    const float* bk     = (const float*)d_in[9];
    const float* Wv     = (const float*)d_in[10];
    const float* bv     = (const float*)d_in[11];
    const float* Wo     = (const float*)d_in[12];
    const float* bo     = (const float*)d_in[13];
    const float* ln2_s  = (const float*)d_in[14];
    const float* ln2_b  = (const float*)d_in[15];
    const float* W1     = (const float*)d_in[16];
    const float* b1     = (const float*)d_in[17];
    const float* W2     = (const float*)d_in[18];
    const float* b2     = (const float*)d_in[19];
    const float* lnf_s  = (const float*)d_in[20];
    const float* lnf_b  = (const float*)d_in[21];
    (void)in_sizes; (void)n_in; (void)out_size; (void)ws_size;

    // ---- workspace: 56 MB + ~28 KB ----
    const size_t MD = (size_t)M_ROWS * DMODEL;            // 4M elems
    float* h     = (float*)d_ws;                          // [0,16) MB
    bf16*  y     = (bf16*)(h + MD);                       // [16,24) MB (LN out / ctx)
    float* yfP   = (float*)(h + MD);                      // same region as fp32 (8 MB)
    bf16*  U     = y + MD;                                // [24,56) MB union
    bf16*  xb    = U;                                     // 16 MB (proj input)
    bf16*  qkv   = U;                                     // 24 MB, stride 3072
    bf16*  mid   = U;                                     // 32 MB (FFN mid)
    float* UfP   = (float*)U;                             // U as fp32 partial (16 MB)
    float* UfP2  = (float*)(U + 8 * 1024 * 1024);         // U second half fp32
    float* vmean = (float*)(U + 16 * 1024 * 1024);        // ws+56 MB, 16 KB
    float* bqkv  = vmean + BATCH * NHEAD * DHEAD;         // 12 KB
    // d_out (16 MB fp32) is scratch until final LN:
    bf16*  wt    = (bf16*)d_out;                          // [0,8) MB: weight^T
    float* doP   = (float*)((char*)d_out + 8 * 1024 * 1024); // [8,16) MB fp32 partial

    const int QS = 3 * DMODEL;   // qkv row stride

    dim3 blk(256);
    dim3 gSK(DMODEL / 128, M_ROWS / 128, 2);              // split-K grid, 512 blocks

    // xb = bf16(x); h = xb @ Wp^T + bp (split-K, P in U upper half); pad+reduce
    cvt_kernel<<<(2 * MD) / (256 * 4), blk, 0, stream>>>(x, xb);
    transpose_kernel<<<dim3(DMODEL / 32, 2048 / 32), blk, 0, stream>>>(Wp, wt, 2048, DMODEL, DMODEL);
    mfma_gemm_sk<<<gSK, blk, 0, stream>>>(xb, wt, bp, h, nullptr,
                                          UfP2, nullptr, M_ROWS, M_ROWS, DMODEL, 2048);
    pad_red_kernel<<<M_ROWS, blk, 0, stream>>>(h, UfP2, xlen);

    for (int l = 0; l < 4; ++l) {
        const size_t wD  = (size_t)l * DMODEL * DMODEL;
        const size_t wF  = (size_t)l * DMODEL * DFF;   // W1 (1024 x 4096)
        const size_t wF2 = (size_t)l * DFF * DMODEL;   // W2 (4096 x 1024)
        const size_t vD  = (size_t)l * DMODEL;
        const size_t vF  = (size_t)l * DFF;

        ln_kernel<bf16, false><<<M_ROWS, blk, 0, stream>>>(h, nullptr,
                                                           ln1_s + vD, ln1_b + vD, y);

        // fused QKV (768 blocks, no split)
        transpose_kernel<<<dim3(32, 32), blk, 0, stream>>>(Wq + wD, wt, DMODEL, DMODEL, DMODEL);
        transpose_kernel<<<dim3(32, 32), blk, 0, stream>>>(Wk + wD, wt + MD / 4, DMODEL, DMODEL, DMODEL);
        transpose_kernel<<<dim3(32, 32), blk, 0, stream>>>(Wv + wD, wt + MD / 2, DMODEL, DMODEL, DMODEL);
        concat3_kernel<<<12, blk, 0, stream>>>(bq + vD, bk + vD, bv + vD, bqkv);
        mfma_gemm<bf16><<<dim3(3 * DMODEL / 128, M_ROWS / 128), blk, 0, stream>>>(
            y, wt, bqkv, qkv, M_ROWS, 3 * DMODEL, DMODEL, 0);

        bf16* qb = qkv;
        bf16* kb = qkv + DMODEL;
        bf16* vb = qkv + 2 * DMODEL;
        rope_kernel<<<(M_ROWS * NHEAD * 64) / 256, blk, 0, stream>>>(qb, kb, QS);
        vmean_kernel<<<BATCH * NHEAD, dim3(DHEAD), 0, stream>>>(vb, vmean, QS);
        attn_kernel<<<BATCH * NHEAD * S_LEN, dim3(64), 0, stream>>>(qb, kb, vb, vmean,
                                                                    xlen, y, QS);

        // h = h + ctx @ Wo^T + bo  (split-K; P in U[0:16) — qkv dead)
        transpose_kernel<<<dim3(32, 32), blk, 0, stream>>>(Wo + wD, wt, DMODEL, DMODEL, DMODEL);
        mfma_gemm_sk<<<gSK, blk, 0, stream>>>(y, wt, bo + vD, h, h,
                                              UfP, nullptr, M_ROWS, M_ROWS, DMODEL, 1024);

        // ln2 fused with Wo's partial reduce: h += P; y = LN(h)
        ln_kernel<bf16, true><<<M_ROWS, blk, 0, stream>>>(h, UfP,
                                                          ln2_s + vD, ln2_b + vD, y);

        // FFN1 full width: mid = silu(y @ W1^T + b1)   (1024 blocks)
        transpose_kernel<<<dim3(DFF / 32, DMODEL / 32), blk, 0, stream>>>(
            W1 + wF, wt, DMODEL, DFF, DFF);
        mfma_gemm<bf16><<<dim3(DFF / 128, M_ROWS / 128), blk, 0, stream>>>(
            y, wt, b1 + vF, mid, M_ROWS, DFF, DMODEL, 1);

        // FFN2 split-K: h = h + mid @ W2^T + b2; P split: rows<2048 -> y-region,
        // rest -> d_out[8:16)  (y dead after FFN1; both regions free)
        transpose_kernel<<<dim3(DMODEL / 32, DFF / 32), blk, 0, stream>>>(
            W2 + wF2, wt, DFF, DMODEL, DMODEL);
        mfma_gemm_sk<<<gSK, blk, 0, stream>>>(mid, wt, b2 + vD, h, h,
                                              yfP, doP, 2048, M_ROWS, DMODEL, DFF);
        reduce2_kernel<<<M_ROWS, blk, 0, stream>>>(h, yfP, doP, 2048);
    }

    ln_kernel<float, false><<<M_ROWS, blk, 0, stream>>>(h, nullptr, lnf_s, lnf_b,
                                                        (float*)d_out);
}